// Round 4
// baseline (82.356 us; speedup 1.0000x reference)
//
#include <hip/hip_runtime.h>

#define HID 16
#define TPB 256

typedef float f2 __attribute__((ext_vector_type(2)));

__device__ __forceinline__ f2 pkfma(f2 a, f2 b, f2 c) {
    return __builtin_elementwise_fma(a, b, c);   // -> v_pk_fma_f32 on gfx950
}

__device__ __forceinline__ float fast_sigmoid(float x) {
    return __builtin_amdgcn_rcpf(1.0f + __expf(-x));
}
__device__ __forceinline__ float fast_tanh(float x) {
    // 2/(1+e^-2x) - 1; overflow -> inf -> rcp -> 0 -> -1 (correct limit)
    return 2.0f * __builtin_amdgcn_rcpf(1.0f + __expf(-2.0f * x)) - 1.0f;
}

// packed dot of uniform weight row (s_loaded, SGPR pairs) with per-lane h2[8]
#define PDOT16(acc, w0, w1, w2, w3, hh)                         \
    {                                                           \
        f2 _wa; _wa.x = w0.x; _wa.y = w0.y;                     \
        f2 _wb; _wb.x = w0.z; _wb.y = w0.w;                     \
        acc = pkfma(_wa, hh[0], acc);                           \
        acc = pkfma(_wb, hh[1], acc);                           \
        _wa.x = w1.x; _wa.y = w1.y;                             \
        _wb.x = w1.z; _wb.y = w1.w;                             \
        acc = pkfma(_wa, hh[2], acc);                           \
        acc = pkfma(_wb, hh[3], acc);                           \
        _wa.x = w2.x; _wa.y = w2.y;                             \
        _wb.x = w2.z; _wb.y = w2.w;                             \
        acc = pkfma(_wa, hh[4], acc);                           \
        acc = pkfma(_wb, hh[5], acc);                           \
        _wa.x = w3.x; _wa.y = w3.y;                             \
        _wb.x = w3.z; _wb.y = w3.w;                             \
        acc = pkfma(_wa, hh[6], acc);                           \
        acc = pkfma(_wb, hh[7], acc);                           \
    }

__global__ __launch_bounds__(TPB) void rssm_kernel(
    const float* __restrict__ prev_z,   // [B,3]
    const float* __restrict__ action,   // [B,1]
    const float* __restrict__ prev_h,   // [B,16]
    const float* __restrict__ W_ih,     // [48,4]
    const float* __restrict__ W_hh,     // [48,16]
    const float* __restrict__ b_ih,     // [48]
    const float* __restrict__ b_hh,     // [48]
    const float* __restrict__ W_mu,     // [3,16]
    const float* __restrict__ b_mu,     // [3]
    const float* __restrict__ W_lv,     // [3,16]
    const float* __restrict__ b_lv,     // [3]
    float* __restrict__ out_mu,         // [B,3]
    float* __restrict__ out_lv,         // [B,3]
    float* __restrict__ out_h,          // [B,16]
    int B)
{
    const int row = blockIdx.x * TPB + threadIdx.x;
    if (row >= B) return;

    // ---- per-lane inputs ----
    const float x0 = prev_z[row * 3 + 0];
    const float x1 = prev_z[row * 3 + 1];
    const float x2 = prev_z[row * 3 + 2];
    const float x3 = action[row];
    f2 x01; x01.x = x0; x01.y = x1;
    f2 x23; x23.x = x2; x23.y = x3;

    f2 h2[8];
    float hj[HID];
    {
        const float4* hp = (const float4*)(prev_h + (size_t)row * HID);
        #pragma unroll
        for (int q = 0; q < 4; ++q) {
            float4 v = hp[q];
            h2[q * 2 + 0].x = v.x; h2[q * 2 + 0].y = v.y;
            h2[q * 2 + 1].x = v.z; h2[q * 2 + 1].y = v.w;
            hj[q * 4 + 0] = v.x; hj[q * 4 + 1] = v.y;
            hj[q * 4 + 2] = v.z; hj[q * 4 + 3] = v.w;
        }
    }

    f2 hn2[8];

    // ---- GRU gates; weight reads wave-uniform -> s_load; math packed (pk_fma) ----
    #pragma unroll
    for (int j = 0; j < HID; ++j) {
        float rv, zv;
        // r gate (row j)
        {
            const float4 wi = *(const float4*)&W_ih[j * 4];
            const float4 w0 = *(const float4*)&W_hh[j * HID + 0];
            const float4 w1 = *(const float4*)&W_hh[j * HID + 4];
            const float4 w2 = *(const float4*)&W_hh[j * HID + 8];
            const float4 w3 = *(const float4*)&W_hh[j * HID + 12];
            f2 acc; acc.x = b_ih[j] + b_hh[j]; acc.y = 0.f;
            f2 wia; wia.x = wi.x; wia.y = wi.y;
            f2 wib; wib.x = wi.z; wib.y = wi.w;
            acc = pkfma(wia, x01, acc);
            acc = pkfma(wib, x23, acc);
            PDOT16(acc, w0, w1, w2, w3, h2);
            rv = fast_sigmoid(acc.x + acc.y);
        }
        // z gate (row 16+j)
        {
            const int g = HID + j;
            const float4 wi = *(const float4*)&W_ih[g * 4];
            const float4 w0 = *(const float4*)&W_hh[g * HID + 0];
            const float4 w1 = *(const float4*)&W_hh[g * HID + 4];
            const float4 w2 = *(const float4*)&W_hh[g * HID + 8];
            const float4 w3 = *(const float4*)&W_hh[g * HID + 12];
            f2 acc; acc.x = b_ih[g] + b_hh[g]; acc.y = 0.f;
            f2 wia; wia.x = wi.x; wia.y = wi.y;
            f2 wib; wib.x = wi.z; wib.y = wi.w;
            acc = pkfma(wia, x01, acc);
            acc = pkfma(wib, x23, acc);
            PDOT16(acc, w0, w1, w2, w3, h2);
            zv = fast_sigmoid(acc.x + acc.y);
        }
        // n gate (row 32+j) + h update
        {
            const int g = 2 * HID + j;
            const float4 wi = *(const float4*)&W_ih[g * 4];
            const float4 w0 = *(const float4*)&W_hh[g * HID + 0];
            const float4 w1 = *(const float4*)&W_hh[g * HID + 4];
            const float4 w2 = *(const float4*)&W_hh[g * HID + 8];
            const float4 w3 = *(const float4*)&W_hh[g * HID + 12];
            f2 ai2; ai2.x = b_ih[g]; ai2.y = 0.f;
            f2 wia; wia.x = wi.x; wia.y = wi.y;
            f2 wib; wib.x = wi.z; wib.y = wi.w;
            ai2 = pkfma(wia, x01, ai2);
            ai2 = pkfma(wib, x23, ai2);
            f2 ah2; ah2.x = b_hh[g]; ah2.y = 0.f;
            PDOT16(ah2, w0, w1, w2, w3, h2);
            const float ai = ai2.x + ai2.y;
            const float ah = ah2.x + ah2.y;
            const float nv = fast_tanh(fmaf(rv, ah, ai));
            const float hnv = fmaf(zv, hj[j] - nv, nv);   // (1-z)*n + z*h
            if (j & 1) hn2[j >> 1].y = hnv; else hn2[j >> 1].x = hnv;
        }
    }

    // ---- heads (packed) ----
    f2 am0; am0.x = b_mu[0]; am0.y = 0.f;
    f2 am1; am1.x = b_mu[1]; am1.y = 0.f;
    f2 am2; am2.x = b_mu[2]; am2.y = 0.f;
    f2 al0; al0.x = b_lv[0]; al0.y = 0.f;
    f2 al1; al1.x = b_lv[1]; al1.y = 0.f;
    f2 al2; al2.x = b_lv[2]; al2.y = 0.f;
    {
        const f2* wm0 = (const f2*)&W_mu[0 * HID];
        const f2* wm1 = (const f2*)&W_mu[1 * HID];
        const f2* wm2 = (const f2*)&W_mu[2 * HID];
        const f2* wl0 = (const f2*)&W_lv[0 * HID];
        const f2* wl1 = (const f2*)&W_lv[1 * HID];
        const f2* wl2 = (const f2*)&W_lv[2 * HID];
        #pragma unroll
        for (int p = 0; p < 8; ++p) {
            am0 = pkfma(wm0[p], hn2[p], am0);
            am1 = pkfma(wm1[p], hn2[p], am1);
            am2 = pkfma(wm2[p], hn2[p], am2);
            al0 = pkfma(wl0[p], hn2[p], al0);
            al1 = pkfma(wl1[p], hn2[p], al1);
            al2 = pkfma(wl2[p], hn2[p], al2);
        }
    }

    // ---- stores: full 64B h row back-to-back ----
    float4* ho = (float4*)(out_h + (size_t)row * HID);
    ho[0] = make_float4(hn2[0].x, hn2[0].y, hn2[1].x, hn2[1].y);
    ho[1] = make_float4(hn2[2].x, hn2[2].y, hn2[3].x, hn2[3].y);
    ho[2] = make_float4(hn2[4].x, hn2[4].y, hn2[5].x, hn2[5].y);
    ho[3] = make_float4(hn2[6].x, hn2[6].y, hn2[7].x, hn2[7].y);

    out_mu[row * 3 + 0] = am0.x + am0.y;
    out_mu[row * 3 + 1] = am1.x + am1.y;
    out_mu[row * 3 + 2] = am2.x + am2.y;
    out_lv[row * 3 + 0] = fminf(fmaxf(al0.x + al0.y, -5.0f), 5.0f);
    out_lv[row * 3 + 1] = fminf(fmaxf(al1.x + al1.y, -5.0f), 5.0f);
    out_lv[row * 3 + 2] = fminf(fmaxf(al2.x + al2.y, -5.0f), 5.0f);
}

extern "C" void kernel_launch(void* const* d_in, const int* in_sizes, int n_in,
                              void* d_out, int out_size, void* d_ws, size_t ws_size,
                              hipStream_t stream) {
    const float* prev_z = (const float*)d_in[0];
    const float* action = (const float*)d_in[1];
    const float* prev_h = (const float*)d_in[2];
    const float* W_ih   = (const float*)d_in[3];
    const float* W_hh   = (const float*)d_in[4];
    const float* b_ih   = (const float*)d_in[5];
    const float* b_hh   = (const float*)d_in[6];
    const float* W_mu   = (const float*)d_in[7];
    const float* b_mu   = (const float*)d_in[8];
    const float* W_lv   = (const float*)d_in[9];
    const float* b_lv   = (const float*)d_in[10];

    const int B = in_sizes[0] / 3;
    float* out    = (float*)d_out;
    float* out_mu = out;
    float* out_lv = out + (size_t)3 * B;
    float* out_h  = out + (size_t)6 * B;

    const int blocks = (B + TPB - 1) / TPB;
    rssm_kernel<<<blocks, TPB, 0, stream>>>(prev_z, action, prev_h,
                                            W_ih, W_hh, b_ih, b_hh,
                                            W_mu, b_mu, W_lv, b_lv,
                                            out_mu, out_lv, out_h, B);
}

// Round 5
// 53.584 us; speedup vs baseline: 1.5370x; 1.5370x over previous
//
#include <hip/hip_runtime.h>

#define HID 16
#define TPB 256

typedef __fp16 h2 __attribute__((ext_vector_type(2)));

#if __has_builtin(__builtin_amdgcn_fdot2)
__device__ __forceinline__ float fdot2(h2 a, h2 b, float c) {
    return __builtin_amdgcn_fdot2(a, b, c, false);   // v_dot2_f32_f16
}
#else
__device__ __forceinline__ float fdot2(h2 a, h2 b, float c) {
    c = fmaf((float)a.x, (float)b.x, c);
    return fmaf((float)a.y, (float)b.y, c);
}
#endif

__device__ __forceinline__ float fast_sigmoid(float x) {
    return __builtin_amdgcn_rcpf(1.0f + __expf(-x));
}
__device__ __forceinline__ float fast_tanh(float x) {
    // 2/(1+e^-2x) - 1; overflow -> inf -> rcp -> 0 -> -1 (correct limit)
    return 2.0f * __builtin_amdgcn_rcpf(1.0f + __expf(-2.0f * x)) - 1.0f;
}

// ---- workspace layout (dwords) ----
// [j*32 + 0  .. +9 ]  r-gate: wi(2) wh(8)   f16x2-packed
// [j*32 + 10 .. +19]  z-gate: wi(2) wh(8)
// [j*32 + 20 .. +29]  n-gate: wi(2) wh(8)
// [512 + j*4 .. +3 ]  biases f32: {b_r = bi+bh, b_z = bi+bh, bn_i, bn_h}
// [576 + m*8 .. +7 ]  head m (0..2 = mu rows, 3..5 = lv rows) f16x2 over k
// [624 + m]           head biases f32 (mu0..2, lv0..2)

__device__ __forceinline__ unsigned pack2(float a, float b) {
    union { __fp16 h[2]; unsigned u; } cv;
    cv.h[0] = (__fp16)a; cv.h[1] = (__fp16)b;
    return cv.u;
}

__global__ __launch_bounds__(64) void prep_kernel(
    const float* __restrict__ W_ih, const float* __restrict__ W_hh,
    const float* __restrict__ b_ih, const float* __restrict__ b_hh,
    const float* __restrict__ W_mu, const float* __restrict__ b_mu,
    const float* __restrict__ W_lv, const float* __restrict__ b_lv,
    unsigned* __restrict__ ws)
{
    const int t = threadIdx.x;
    if (t < HID) {
        #pragma unroll
        for (int gi = 0; gi < 3; ++gi) {
            const int g = gi * HID + t;
            unsigned* dst = ws + t * 32 + gi * 10;
            dst[0] = pack2(W_ih[g * 4 + 0], W_ih[g * 4 + 1]);
            dst[1] = pack2(W_ih[g * 4 + 2], W_ih[g * 4 + 3]);
            #pragma unroll
            for (int k = 0; k < 8; ++k)
                dst[2 + k] = pack2(W_hh[g * HID + 2 * k], W_hh[g * HID + 2 * k + 1]);
        }
        float* bz = (float*)(ws + 512 + t * 4);
        bz[0] = b_ih[t] + b_hh[t];
        bz[1] = b_ih[HID + t] + b_hh[HID + t];
        bz[2] = b_ih[2 * HID + t];
        bz[3] = b_hh[2 * HID + t];
    }
    if (t < 6) {
        const float* src = (t < 3) ? &W_mu[t * HID] : &W_lv[(t - 3) * HID];
        unsigned* dst = ws + 576 + t * 8;
        #pragma unroll
        for (int k = 0; k < 8; ++k)
            dst[k] = pack2(src[2 * k], src[2 * k + 1]);
        float* hb = (float*)(ws + 624);
        hb[t] = (t < 3) ? b_mu[t] : b_lv[t - 3];
    }
}

__global__ __launch_bounds__(TPB) void rssm_kernel(
    const float* __restrict__ prev_z,   // [B,3]
    const float* __restrict__ action,   // [B,1]
    const float* __restrict__ prev_h,   // [B,16]
    const unsigned* __restrict__ ws,    // packed weights (see layout)
    float* __restrict__ out_mu,         // [B,3]
    float* __restrict__ out_lv,         // [B,3]
    float* __restrict__ out_h,          // [B,16]
    int B)
{
    const int row = blockIdx.x * TPB + threadIdx.x;
    if (row >= B) return;

    // ---- per-lane inputs ----
    const float x0 = prev_z[row * 3 + 0];
    const float x1 = prev_z[row * 3 + 1];
    const float x2 = prev_z[row * 3 + 2];
    const float x3 = action[row];
    h2 x01; x01.x = (__fp16)x0; x01.y = (__fp16)x1;
    h2 x23; x23.x = (__fp16)x2; x23.y = (__fp16)x3;

    // h in f32 (for the z*h_prev update) and packed f16 (for dots)
    float hf[HID];
    h2 hx[8];
    {
        const float4* hp = (const float4*)(prev_h + (size_t)row * HID);
        #pragma unroll
        for (int q = 0; q < 4; ++q) {
            float4 v = hp[q];
            hf[q*4+0] = v.x; hf[q*4+1] = v.y; hf[q*4+2] = v.z; hf[q*4+3] = v.w;
            hx[q*2+0].x = (__fp16)v.x; hx[q*2+0].y = (__fp16)v.y;
            hx[q*2+1].x = (__fp16)v.z; hx[q*2+1].y = (__fp16)v.w;
        }
    }

    const h2* wbase = (const h2*)ws;
    const float* BS = (const float*)(ws + 512);

    float hn[HID];

    #pragma unroll 4
    for (int j = 0; j < HID; ++j) {
        const h2* wr = wbase + j * 32;       // r: wr[0..9]
        const h2* wz = wr + 10;              // z
        const h2* wn = wr + 20;              // n
        const float4 bb = *(const float4*)&BS[j * 4]; // {b_r, b_z, bn_i, bn_h}

        float ar = bb.x;
        ar = fdot2(wr[0], x01, ar); ar = fdot2(wr[1], x23, ar);
        #pragma unroll
        for (int k = 0; k < 8; ++k) ar = fdot2(wr[2 + k], hx[k], ar);
        const float rv = fast_sigmoid(ar);

        float az = bb.y;
        az = fdot2(wz[0], x01, az); az = fdot2(wz[1], x23, az);
        #pragma unroll
        for (int k = 0; k < 8; ++k) az = fdot2(wz[2 + k], hx[k], az);
        const float zv = fast_sigmoid(az);

        float ai = bb.z;
        ai = fdot2(wn[0], x01, ai); ai = fdot2(wn[1], x23, ai);
        float ah = bb.w;
        #pragma unroll
        for (int k = 0; k < 8; ++k) ah = fdot2(wn[2 + k], hx[k], ah);
        const float nv = fast_tanh(fmaf(rv, ah, ai));
        hn[j] = fmaf(zv, hf[j] - nv, nv);    // (1-z)*n + z*h
    }

    // ---- heads: 6 dots of 16 via dot2 ----
    h2 hn16[8];
    #pragma unroll
    for (int k = 0; k < 8; ++k) {
        hn16[k].x = (__fp16)hn[2 * k];
        hn16[k].y = (__fp16)hn[2 * k + 1];
    }
    const h2* HW = (const h2*)(ws + 576);
    const float* HB = (const float*)(ws + 624);
    float acc[6];
    #pragma unroll
    for (int m = 0; m < 6; ++m) {
        float a = HB[m];
        #pragma unroll
        for (int k = 0; k < 8; ++k) a = fdot2(HW[m * 8 + k], hn16[k], a);
        acc[m] = a;
    }

    // ---- stores: full 64B h row back-to-back ----
    float4* ho = (float4*)(out_h + (size_t)row * HID);
    ho[0] = make_float4(hn[0],  hn[1],  hn[2],  hn[3]);
    ho[1] = make_float4(hn[4],  hn[5],  hn[6],  hn[7]);
    ho[2] = make_float4(hn[8],  hn[9],  hn[10], hn[11]);
    ho[3] = make_float4(hn[12], hn[13], hn[14], hn[15]);

    out_mu[row * 3 + 0] = acc[0];
    out_mu[row * 3 + 1] = acc[1];
    out_mu[row * 3 + 2] = acc[2];
    out_lv[row * 3 + 0] = fminf(fmaxf(acc[3], -5.0f), 5.0f);
    out_lv[row * 3 + 1] = fminf(fmaxf(acc[4], -5.0f), 5.0f);
    out_lv[row * 3 + 2] = fminf(fmaxf(acc[5], -5.0f), 5.0f);
}

extern "C" void kernel_launch(void* const* d_in, const int* in_sizes, int n_in,
                              void* d_out, int out_size, void* d_ws, size_t ws_size,
                              hipStream_t stream) {
    const float* prev_z = (const float*)d_in[0];
    const float* action = (const float*)d_in[1];
    const float* prev_h = (const float*)d_in[2];
    const float* W_ih   = (const float*)d_in[3];
    const float* W_hh   = (const float*)d_in[4];
    const float* b_ih   = (const float*)d_in[5];
    const float* b_hh   = (const float*)d_in[6];
    const float* W_mu   = (const float*)d_in[7];
    const float* b_mu   = (const float*)d_in[8];
    const float* W_lv   = (const float*)d_in[9];
    const float* b_lv   = (const float*)d_in[10];

    const int B = in_sizes[0] / 3;
    float* out    = (float*)d_out;
    float* out_mu = out;
    float* out_lv = out + (size_t)3 * B;
    float* out_h  = out + (size_t)6 * B;
    unsigned* ws  = (unsigned*)d_ws;   // needs 630 dwords (~2.6 KB)

    prep_kernel<<<1, 64, 0, stream>>>(W_ih, W_hh, b_ih, b_hh,
                                      W_mu, b_mu, W_lv, b_lv, ws);

    const int blocks = (B + TPB - 1) / TPB;
    rssm_kernel<<<blocks, TPB, 0, stream>>>(prev_z, action, prev_h, ws,
                                            out_mu, out_lv, out_h, B);
}

// Round 6
// 52.513 us; speedup vs baseline: 1.5683x; 1.0204x over previous
//
#include <hip/hip_runtime.h>

#define TPB 256

typedef _Float16 half8 __attribute__((ext_vector_type(8)));
typedef float f32x4 __attribute__((ext_vector_type(4)));

__device__ __forceinline__ float fast_sigmoid(float x) {
    return __builtin_amdgcn_rcpf(1.0f + __expf(-x));
}
__device__ __forceinline__ float fast_tanh(float x) {
    // 2/(1+e^-2x) - 1; overflow -> inf -> rcp -> 0 -> -1 (correct limit)
    return 2.0f * __builtin_amdgcn_rcpf(1.0f + __expf(-2.0f * x)) - 1.0f;
}

// ---- ws layout (bytes) ----
// 0    : B tiles, 4 tiles x [64 lanes x 8 halfs]   = 4096   (r, z, n_i, n_h)
// 4096 : A2 head fragment, 64 lanes x 8 halfs      = 1024
// 5120 : biases f32: b_r[16] b_z[16] b_ni[16] b_nh[16] = 256
//
// Main GEMM: D[16 rows x 16 gates] = A[16 x 32] * B[32 x 16] + bias
//   A k-layout: k0-3 = x (z0,z1,z2,action), k4-19 = h0..15, k20-31 = 0
// Head GEMM: D2[16 heads x 16 rows] = A2[16 x 32] * B2[32 x 16]
//   A2 rows m: 0-2 = W_mu, 3-5 = W_lv, k16..31 zero except k20 = bias[m]
//   B2[k][n] = hn[row=n][k] for k<16; B2[20][n] = 1.0 (bias slot)

__global__ __launch_bounds__(64) void prep_kernel(
    const float* __restrict__ W_ih, const float* __restrict__ W_hh,
    const float* __restrict__ b_ih, const float* __restrict__ b_hh,
    const float* __restrict__ W_mu, const float* __restrict__ b_mu,
    const float* __restrict__ W_lv, const float* __restrict__ b_lv,
    void* __restrict__ wsv)
{
    _Float16* wsB  = (_Float16*)wsv;
    _Float16* wsA2 = wsB + 2048;
    float*    wsBias = (float*)((char*)wsv + 5120);
    const int l = threadIdx.x;
    const int col = l & 15, kg = l >> 4;

    // B tiles: lane l holds B[k = kg*8+i][n = col]
    #pragma unroll
    for (int t = 0; t < 4; ++t) {
        const int gate = (t == 0) ? col : (t == 1) ? (16 + col) : (32 + col);
        #pragma unroll
        for (int i = 0; i < 8; ++i) {
            const int k = kg * 8 + i;
            float v = 0.f;
            if (t <= 1) {                       // r, z: x part + h part
                if (k < 4)       v = W_ih[gate * 4 + k];
                else if (k < 20) v = W_hh[gate * 16 + (k - 4)];
            } else if (t == 2) {                // n_i: x part only
                if (k < 4)       v = W_ih[gate * 4 + k];
            } else {                            // n_h: h part only
                if (k >= 4 && k < 20) v = W_hh[gate * 16 + (k - 4)];
            }
            wsB[t * 512 + l * 8 + i] = (_Float16)v;
        }
    }
    // A2: lane l holds A2[row m = col][k = kg*8+i]
    #pragma unroll
    for (int i = 0; i < 8; ++i) {
        const int k = kg * 8 + i;
        const int m = col;
        float v = 0.f;
        if (m < 3) {
            if (k < 16)      v = W_mu[m * 16 + k];
            else if (k == 20) v = b_mu[m];
        } else if (m < 6) {
            if (k < 16)      v = W_lv[(m - 3) * 16 + k];
            else if (k == 20) v = b_lv[m - 3];
        }
        wsA2[l * 8 + i] = (_Float16)v;
    }
    if (l < 16) {
        wsBias[l]      = b_ih[l] + b_hh[l];            // r
        wsBias[16 + l] = b_ih[16 + l] + b_hh[16 + l];  // z
        wsBias[32 + l] = b_ih[32 + l];                 // n_i
        wsBias[48 + l] = b_hh[32 + l];                 // n_h
    }
}

__global__ __launch_bounds__(TPB) void rssm_kernel(
    const float* __restrict__ prev_z,   // [B,3]
    const float* __restrict__ action,   // [B,1]
    const float* __restrict__ prev_h,   // [B,16]
    const void*  __restrict__ wsv,
    float* __restrict__ out_mu,         // [B,3]
    float* __restrict__ out_lv,         // [B,3]
    float* __restrict__ out_h,          // [B,16]
    int B)
{
    __shared__ float lds[4][16 * 20];   // per-wave hn tile, stride 20 dwords
    const int tid  = threadIdx.x;
    const int wid  = tid >> 6, lane = tid & 63;
    const int col  = lane & 15, kg = lane >> 4;
    const int base = (blockIdx.x * 4 + wid) * 16;
    if (base >= B) return;

    const _Float16* wsB  = (const _Float16*)wsv;
    const _Float16* wsA2 = wsB + 2048;
    const float*    wsBias = (const float*)((const char*)wsv + 5120);

    // ---- A fragment: lane holds A[row = col][k = kg*8+i] ----
    const int arow = min(base + col, B - 1);
    half8 a;
    if (kg == 0) {
        const float z0 = prev_z[arow * 3 + 0];
        const float z1 = prev_z[arow * 3 + 1];
        const float z2 = prev_z[arow * 3 + 2];
        const float ac = action[arow];
        const float4 h03 = *(const float4*)(prev_h + (size_t)arow * 16);
        a[0] = (_Float16)z0;    a[1] = (_Float16)z1;
        a[2] = (_Float16)z2;    a[3] = (_Float16)ac;
        a[4] = (_Float16)h03.x; a[5] = (_Float16)h03.y;
        a[6] = (_Float16)h03.z; a[7] = (_Float16)h03.w;
    } else if (kg == 1) {
        const float4 u = *(const float4*)(prev_h + (size_t)arow * 16 + 4);
        const float4 v = *(const float4*)(prev_h + (size_t)arow * 16 + 8);
        a[0] = (_Float16)u.x; a[1] = (_Float16)u.y;
        a[2] = (_Float16)u.z; a[3] = (_Float16)u.w;
        a[4] = (_Float16)v.x; a[5] = (_Float16)v.y;
        a[6] = (_Float16)v.z; a[7] = (_Float16)v.w;
    } else if (kg == 2) {
        const float4 w = *(const float4*)(prev_h + (size_t)arow * 16 + 12);
        a[0] = (_Float16)w.x; a[1] = (_Float16)w.y;
        a[2] = (_Float16)w.z; a[3] = (_Float16)w.w;
        a[4] = (_Float16)0.f; a[5] = (_Float16)0.f;
        a[6] = (_Float16)0.f; a[7] = (_Float16)0.f;
    } else {
        #pragma unroll
        for (int i = 0; i < 8; ++i) a[i] = (_Float16)0.f;
    }

    // ---- B fragments (prepacked, lane-ordered) ----
    const half8* Bp = (const half8*)wsB;
    const half8 bR  = Bp[lane];
    const half8 bZ  = Bp[64 + lane];
    const half8 bNi = Bp[128 + lane];
    const half8 bNh = Bp[192 + lane];

    // ---- acc init with biases (bias per gate col; same for all 4 row-regs) ----
    const float br  = wsBias[col];
    const float bz  = wsBias[16 + col];
    const float bni = wsBias[32 + col];
    const float bnh = wsBias[48 + col];
    f32x4 accR  = {br,  br,  br,  br};
    f32x4 accZ  = {bz,  bz,  bz,  bz};
    f32x4 accNi = {bni, bni, bni, bni};
    f32x4 accNh = {bnh, bnh, bnh, bnh};

    accR  = __builtin_amdgcn_mfma_f32_16x16x32_f16(a, bR,  accR,  0, 0, 0);
    accZ  = __builtin_amdgcn_mfma_f32_16x16x32_f16(a, bZ,  accZ,  0, 0, 0);
    accNi = __builtin_amdgcn_mfma_f32_16x16x32_f16(a, bNi, accNi, 0, 0, 0);
    accNh = __builtin_amdgcn_mfma_f32_16x16x32_f16(a, bNh, accNh, 0, 0, 0);

    // ---- gates + h update; D layout: col = gate j = lane&15, row = kg*4+q ----
    const int rbase = base + kg * 4;
    #pragma unroll
    for (int q = 0; q < 4; ++q) {
        const int rr = min(rbase + q, B - 1);
        const float hp = prev_h[(size_t)rr * 16 + col];
        const float r  = fast_sigmoid(accR[q]);
        const float z  = fast_sigmoid(accZ[q]);
        const float n  = fast_tanh(fmaf(r, accNh[q], accNi[q]));
        const float hv = fmaf(z, hp - n, n);           // (1-z)*n + z*h
        if (rbase + q < B) out_h[(size_t)rr * 16 + col] = hv;
        lds[wid][(kg * 4 + q) * 20 + col] = hv;
    }

    // ---- head B2 fragment: B2[k][n=col] = hn[row=col][k] (wave-local transpose) ----
    half8 b2;
    if (kg < 2) {
        const float* src = &lds[wid][col * 20 + kg * 8];
        #pragma unroll
        for (int i = 0; i < 8; ++i) b2[i] = (_Float16)src[i];
    } else if (kg == 2) {
        #pragma unroll
        for (int i = 0; i < 8; ++i) b2[i] = (_Float16)0.f;
        b2[4] = (_Float16)1.0f;     // k = 20: bias slot
    } else {
        #pragma unroll
        for (int i = 0; i < 8; ++i) b2[i] = (_Float16)0.f;
    }

    const half8 a2 = ((const half8*)wsA2)[lane];
    f32x4 acc2 = {0.f, 0.f, 0.f, 0.f};
    acc2 = __builtin_amdgcn_mfma_f32_16x16x32_f16(a2, b2, acc2, 0, 0, 0);

    // ---- D2 layout: col = batch row (lane&15), row m = kg*4+q (m<6 valid) ----
    const int brow = base + col;
    if (brow < B) {
        if (kg == 0) {
            out_mu[brow * 3 + 0] = acc2[0];
            out_mu[brow * 3 + 1] = acc2[1];
            out_mu[brow * 3 + 2] = acc2[2];
            out_lv[brow * 3 + 0] = fminf(fmaxf(acc2[3], -5.0f), 5.0f);
        } else if (kg == 1) {
            out_lv[brow * 3 + 1] = fminf(fmaxf(acc2[0], -5.0f), 5.0f);
            out_lv[brow * 3 + 2] = fminf(fmaxf(acc2[1], -5.0f), 5.0f);
        }
    }
}

extern "C" void kernel_launch(void* const* d_in, const int* in_sizes, int n_in,
                              void* d_out, int out_size, void* d_ws, size_t ws_size,
                              hipStream_t stream) {
    const float* prev_z = (const float*)d_in[0];
    const float* action = (const float*)d_in[1];
    const float* prev_h = (const float*)d_in[2];
    const float* W_ih   = (const float*)d_in[3];
    const float* W_hh   = (const float*)d_in[4];
    const float* b_ih   = (const float*)d_in[5];
    const float* b_hh   = (const float*)d_in[6];
    const float* W_mu   = (const float*)d_in[7];
    const float* b_mu   = (const float*)d_in[8];
    const float* W_lv   = (const float*)d_in[9];
    const float* b_lv   = (const float*)d_in[10];

    const int B = in_sizes[0] / 3;
    float* out    = (float*)d_out;
    float* out_mu = out;
    float* out_lv = out + (size_t)3 * B;
    float* out_h  = out + (size_t)6 * B;

    prep_kernel<<<1, 64, 0, stream>>>(W_ih, W_hh, b_ih, b_hh,
                                      W_mu, b_mu, W_lv, b_lv, d_ws);

    const int blocks = (B + 63) / 64;   // 64 rows per block (4 waves x 16 rows)
    rssm_kernel<<<blocks, TPB, 0, stream>>>(prev_z, action, prev_h, d_ws,
                                            out_mu, out_lv, out_h, B);
}

// Round 7
// 51.739 us; speedup vs baseline: 1.5918x; 1.0150x over previous
//
#include <hip/hip_runtime.h>

#define TPB 256
#define WPT 4   // 16-row subtiles per wave -> 64 rows/wave, 256 rows/block

typedef _Float16 half8 __attribute__((ext_vector_type(8)));
typedef float f32x4 __attribute__((ext_vector_type(4)));

__device__ __forceinline__ float fast_sigmoid(float x) {
    return __builtin_amdgcn_rcpf(1.0f + __expf(-x));
}
__device__ __forceinline__ float fast_tanh(float x) {
    // 2/(1+e^-2x) - 1; overflow -> inf -> rcp -> 0 -> -1 (correct limit)
    return 2.0f * __builtin_amdgcn_rcpf(1.0f + __expf(-2.0f * x)) - 1.0f;
}

// ---- ws layout (bytes) ----
// 0    : B tiles, 4 tiles x [64 lanes x 8 halfs] = 4096   (r, z, n_i, n_h)
// 4096 : A2 head fragment, 64 lanes x 8 halfs    = 1024
// 5120 : biases float4[16]: per gate col {b_r, b_z, b_ni, b_nh} = 256
//
// Main GEMM: D[16 rows x 16 gates] = A[16 x 32] * B[32 x 16] + bias
//   A k-layout: k0-3 = x (z0,z1,z2,action), k4-19 = h0..15, k20-31 = 0
// Head GEMM: D2[16 heads x 16 rows] = A2[16 x 32] * B2[32 x 16]
//   A2 rows m: 0-2 = W_mu, 3-5 = W_lv; k20 = bias slot (B2[20][n] = 1.0)

__global__ __launch_bounds__(64) void prep_kernel(
    const float* __restrict__ W_ih, const float* __restrict__ W_hh,
    const float* __restrict__ b_ih, const float* __restrict__ b_hh,
    const float* __restrict__ W_mu, const float* __restrict__ b_mu,
    const float* __restrict__ W_lv, const float* __restrict__ b_lv,
    void* __restrict__ wsv)
{
    _Float16* wsB  = (_Float16*)wsv;
    _Float16* wsA2 = wsB + 2048;
    const int l = threadIdx.x;
    const int col = l & 15, kg = l >> 4;

    // B tiles: lane l holds B[k = kg*8+i][n = col]
    #pragma unroll
    for (int t = 0; t < 4; ++t) {
        const int gate = (t == 0) ? col : (t == 1) ? (16 + col) : (32 + col);
        #pragma unroll
        for (int i = 0; i < 8; ++i) {
            const int k = kg * 8 + i;
            float v = 0.f;
            if (t <= 1) {                       // r, z: x part + h part
                if (k < 4)       v = W_ih[gate * 4 + k];
                else if (k < 20) v = W_hh[gate * 16 + (k - 4)];
            } else if (t == 2) {                // n_i: x part only
                if (k < 4)       v = W_ih[gate * 4 + k];
            } else {                            // n_h: h part only
                if (k >= 4 && k < 20) v = W_hh[gate * 16 + (k - 4)];
            }
            wsB[t * 512 + l * 8 + i] = (_Float16)v;
        }
    }
    // A2: lane l holds A2[row m = col][k = kg*8+i]
    #pragma unroll
    for (int i = 0; i < 8; ++i) {
        const int k = kg * 8 + i;
        const int m = col;
        float v = 0.f;
        if (m < 3) {
            if (k < 16)       v = W_mu[m * 16 + k];
            else if (k == 20) v = b_mu[m];
        } else if (m < 6) {
            if (k < 16)       v = W_lv[(m - 3) * 16 + k];
            else if (k == 20) v = b_lv[m - 3];
        }
        wsA2[l * 8 + i] = (_Float16)v;
    }
    if (l < 16) {
        float4* b4 = (float4*)((char*)wsv + 5120);
        b4[l] = make_float4(b_ih[l] + b_hh[l],
                            b_ih[16 + l] + b_hh[16 + l],
                            b_ih[32 + l],
                            b_hh[32 + l]);
    }
}

__global__ __launch_bounds__(TPB) void rssm_kernel(
    const float* __restrict__ prev_z,   // [B,3]
    const float* __restrict__ action,   // [B,1]
    const float* __restrict__ prev_h,   // [B,16]
    const void*  __restrict__ wsv,
    float* __restrict__ out_mu,         // [B,3]
    float* __restrict__ out_lv,         // [B,3]
    float* __restrict__ out_h,          // [B,16]
    int B)
{
    __shared__ float lds[4][WPT][16 * 20];   // per-wave, per-subtile hn tiles
    const int tid  = threadIdx.x;
    const int wid  = tid >> 6, lane = tid & 63;
    const int col  = lane & 15, kg = lane >> 4;
    const int wbase = (blockIdx.x * 4 + wid) * (16 * WPT);
    if (wbase >= B) return;

    const _Float16* wsB  = (const _Float16*)wsv;
    const _Float16* wsA2 = wsB + 2048;
    const float4*   wsB4 = (const float4*)((const char*)wsv + 5120);

    // ---- wave-invariant fragments (once per 64 rows) ----
    const half8* Bp = (const half8*)wsB;
    const half8 bR  = Bp[lane];
    const half8 bZ  = Bp[64 + lane];
    const half8 bNi = Bp[128 + lane];
    const half8 bNh = Bp[192 + lane];
    const half8 a2  = ((const half8*)wsA2)[lane];
    const float4 bias = wsB4[col];    // {b_r, b_z, b_ni, b_nh}

    // ---- A fragments for all WPT tiles (issue loads up front) ----
    half8 a[WPT];
    if (kg == 0) {
        #pragma unroll
        for (int t = 0; t < WPT; ++t) {
            const int arow = min(wbase + t * 16 + col, B - 1);
            const float z0 = prev_z[arow * 3 + 0];
            const float z1 = prev_z[arow * 3 + 1];
            const float z2 = prev_z[arow * 3 + 2];
            const float ac = action[arow];
            const float4 h03 = *(const float4*)(prev_h + (size_t)arow * 16);
            a[t][0] = (_Float16)z0;    a[t][1] = (_Float16)z1;
            a[t][2] = (_Float16)z2;    a[t][3] = (_Float16)ac;
            a[t][4] = (_Float16)h03.x; a[t][5] = (_Float16)h03.y;
            a[t][6] = (_Float16)h03.z; a[t][7] = (_Float16)h03.w;
        }
    } else if (kg == 1) {
        #pragma unroll
        for (int t = 0; t < WPT; ++t) {
            const int arow = min(wbase + t * 16 + col, B - 1);
            const float4 u = *(const float4*)(prev_h + (size_t)arow * 16 + 4);
            const float4 v = *(const float4*)(prev_h + (size_t)arow * 16 + 8);
            a[t][0] = (_Float16)u.x; a[t][1] = (_Float16)u.y;
            a[t][2] = (_Float16)u.z; a[t][3] = (_Float16)u.w;
            a[t][4] = (_Float16)v.x; a[t][5] = (_Float16)v.y;
            a[t][6] = (_Float16)v.z; a[t][7] = (_Float16)v.w;
        }
    } else if (kg == 2) {
        #pragma unroll
        for (int t = 0; t < WPT; ++t) {
            const int arow = min(wbase + t * 16 + col, B - 1);
            const float4 w = *(const float4*)(prev_h + (size_t)arow * 16 + 12);
            a[t][0] = (_Float16)w.x; a[t][1] = (_Float16)w.y;
            a[t][2] = (_Float16)w.z; a[t][3] = (_Float16)w.w;
            a[t][4] = (_Float16)0.f; a[t][5] = (_Float16)0.f;
            a[t][6] = (_Float16)0.f; a[t][7] = (_Float16)0.f;
        }
    } else {
        #pragma unroll
        for (int t = 0; t < WPT; ++t)
            #pragma unroll
            for (int i = 0; i < 8; ++i) a[t][i] = (_Float16)0.f;
    }

    // ---- prev_h re-reads for the gate epilogue (issue up front, L1-hot) ----
    float hp[WPT][4];
    #pragma unroll
    for (int t = 0; t < WPT; ++t) {
        const int rbase = wbase + t * 16 + kg * 4;
        #pragma unroll
        for (int q = 0; q < 4; ++q)
            hp[t][q] = prev_h[(size_t)min(rbase + q, B - 1) * 16 + col];
    }

    // ---- gate phase: 4 MFMA + epilogue + LDS write per tile ----
    #pragma unroll
    for (int t = 0; t < WPT; ++t) {
        f32x4 accR  = {bias.x, bias.x, bias.x, bias.x};
        f32x4 accZ  = {bias.y, bias.y, bias.y, bias.y};
        f32x4 accNi = {bias.z, bias.z, bias.z, bias.z};
        f32x4 accNh = {bias.w, bias.w, bias.w, bias.w};
        accR  = __builtin_amdgcn_mfma_f32_16x16x32_f16(a[t], bR,  accR,  0, 0, 0);
        accZ  = __builtin_amdgcn_mfma_f32_16x16x32_f16(a[t], bZ,  accZ,  0, 0, 0);
        accNi = __builtin_amdgcn_mfma_f32_16x16x32_f16(a[t], bNi, accNi, 0, 0, 0);
        accNh = __builtin_amdgcn_mfma_f32_16x16x32_f16(a[t], bNh, accNh, 0, 0, 0);

        const int rbase = wbase + t * 16 + kg * 4;
        float* ldst = &lds[wid][t][0];
        #pragma unroll
        for (int q = 0; q < 4; ++q) {
            const float r  = fast_sigmoid(accR[q]);
            const float z  = fast_sigmoid(accZ[q]);
            const float n  = fast_tanh(fmaf(r, accNh[q], accNi[q]));
            const float hv = fmaf(z, hp[t][q] - n, n);       // (1-z)*n + z*h
            const int rr = rbase + q;
            if (rr < B) out_h[(size_t)min(rr, B - 1) * 16 + col] = hv;
            ldst[(kg * 4 + q) * 20 + col] = hv;
        }
    }

    // ---- head phase: one transpose-read + MFMA + store per tile ----
    #pragma unroll
    for (int t = 0; t < WPT; ++t) {
        half8 b2;
        if (kg < 2) {
            const float4 p0 = *(const float4*)&lds[wid][t][col * 20 + kg * 8];
            const float4 p1 = *(const float4*)&lds[wid][t][col * 20 + kg * 8 + 4];
            b2[0] = (_Float16)p0.x; b2[1] = (_Float16)p0.y;
            b2[2] = (_Float16)p0.z; b2[3] = (_Float16)p0.w;
            b2[4] = (_Float16)p1.x; b2[5] = (_Float16)p1.y;
            b2[6] = (_Float16)p1.z; b2[7] = (_Float16)p1.w;
        } else if (kg == 2) {
            #pragma unroll
            for (int i = 0; i < 8; ++i) b2[i] = (_Float16)0.f;
            b2[4] = (_Float16)1.0f;    // k = 20: bias slot
        } else {
            #pragma unroll
            for (int i = 0; i < 8; ++i) b2[i] = (_Float16)0.f;
        }

        f32x4 acc2 = {0.f, 0.f, 0.f, 0.f};
        acc2 = __builtin_amdgcn_mfma_f32_16x16x32_f16(a2, b2, acc2, 0, 0, 0);

        const int brow = wbase + t * 16 + col;
        if (brow < B) {
            if (kg == 0) {
                out_mu[brow * 3 + 0] = acc2[0];
                out_mu[brow * 3 + 1] = acc2[1];
                out_mu[brow * 3 + 2] = acc2[2];
                out_lv[brow * 3 + 0] = fminf(fmaxf(acc2[3], -5.0f), 5.0f);
            } else if (kg == 1) {
                out_lv[brow * 3 + 1] = fminf(fmaxf(acc2[0], -5.0f), 5.0f);
                out_lv[brow * 3 + 2] = fminf(fmaxf(acc2[1], -5.0f), 5.0f);
            }
        }
    }
}

extern "C" void kernel_launch(void* const* d_in, const int* in_sizes, int n_in,
                              void* d_out, int out_size, void* d_ws, size_t ws_size,
                              hipStream_t stream) {
    const float* prev_z = (const float*)d_in[0];
    const float* action = (const float*)d_in[1];
    const float* prev_h = (const float*)d_in[2];
    const float* W_ih   = (const float*)d_in[3];
    const float* W_hh   = (const float*)d_in[4];
    const float* b_ih   = (const float*)d_in[5];
    const float* b_hh   = (const float*)d_in[6];
    const float* W_mu   = (const float*)d_in[7];
    const float* b_mu   = (const float*)d_in[8];
    const float* W_lv   = (const float*)d_in[9];
    const float* b_lv   = (const float*)d_in[10];

    const int B = in_sizes[0] / 3;
    float* out    = (float*)d_out;
    float* out_mu = out;
    float* out_lv = out + (size_t)3 * B;
    float* out_h  = out + (size_t)6 * B;

    prep_kernel<<<1, 64, 0, stream>>>(W_ih, W_hh, b_ih, b_hh,
                                      W_mu, b_mu, W_lv, b_lv, d_ws);

    const int rows_per_block = 4 * 16 * WPT;   // 256
    const int blocks = (B + rows_per_block - 1) / rows_per_block;
    rssm_kernel<<<blocks, TPB, 0, stream>>>(prev_z, action, prev_h, d_ws,
                                            out_mu, out_lv, out_h, B);
}

// Round 9
// 42.947 us; speedup vs baseline: 1.9176x; 1.2047x over previous
//
#include <hip/hip_runtime.h>

#define TPB 256
#define WPT 4                 // 16-row tiles per wave -> 64 rows/wave, 256/block
#define ROW_DW 20             // per-row LDS: xa[4] + h[16] dwords
#define LDS_ROW_F32 (64 * ROW_DW)        // 1280
#define LDS_MU_F32 192                    // 64 rows x 3
#define LDS_WAVE_F32 (LDS_ROW_F32 + 2 * LDS_MU_F32)   // 1664 f32 = 6656 B

typedef _Float16 half8 __attribute__((ext_vector_type(8)));
typedef __fp16  fp16x2 __attribute__((ext_vector_type(2)));
typedef float f32x4 __attribute__((ext_vector_type(4)));

__device__ __forceinline__ float fast_sigmoid(float x) {
    return __builtin_amdgcn_rcpf(1.0f + __expf(-x));
}
__device__ __forceinline__ float fast_tanh(float x) {
    return 2.0f * __builtin_amdgcn_rcpf(1.0f + __expf(-2.0f * x)) - 1.0f;
}
__device__ __forceinline__ half8 pack8(float4 lo, float4 hi) {
    union { fp16x2 p[4]; half8 h; } u;
    u.p[0] = __builtin_amdgcn_cvt_pkrtz(lo.x, lo.y);
    u.p[1] = __builtin_amdgcn_cvt_pkrtz(lo.z, lo.w);
    u.p[2] = __builtin_amdgcn_cvt_pkrtz(hi.x, hi.y);
    u.p[3] = __builtin_amdgcn_cvt_pkrtz(hi.z, hi.w);
    return u.h;
}

// ---- ws layout ----
// halfs: 6 tiles x 512 halfs (r, z, n_i, n_h, hp-identity, A2) = 6144 B
// byte 6144: float4 bias[16] per gate col {b_r, b_z, b_ni, b_nh} = 256 B
// A k-map: k0-3 = x(z0,z1,z2,act), k4-19 = h0..15, k20-31 = 0
// A2 rows m: 0-2 = W_mu, 3-5 = W_lv; k20 = bias slot (B2[20][n] = 1.0)

__global__ __launch_bounds__(64) void prep_kernel(
    const float* __restrict__ W_ih, const float* __restrict__ W_hh,
    const float* __restrict__ b_ih, const float* __restrict__ b_hh,
    const float* __restrict__ W_mu, const float* __restrict__ b_mu,
    const float* __restrict__ W_lv, const float* __restrict__ b_lv,
    void* __restrict__ wsv)
{
    _Float16* wsB = (_Float16*)wsv;
    const int l = threadIdx.x;
    const int col = l & 15, kg = l >> 4;

    // gate B tiles: lane l holds B[k = kg*8+i][n = col]
    #pragma unroll
    for (int t = 0; t < 4; ++t) {
        const int gate = (t == 0) ? col : (t == 1) ? (16 + col) : (32 + col);
        #pragma unroll
        for (int i = 0; i < 8; ++i) {
            const int k = kg * 8 + i;
            float v = 0.f;
            if (t <= 1) {
                if (k < 4)       v = W_ih[gate * 4 + k];
                else if (k < 20) v = W_hh[gate * 16 + (k - 4)];
            } else if (t == 2) {
                if (k < 4)       v = W_ih[gate * 4 + k];
            } else {
                if (k >= 4 && k < 20) v = W_hh[gate * 16 + (k - 4)];
            }
            wsB[t * 512 + l * 8 + i] = (_Float16)v;
        }
    }
    // tile 4: hp identity  B[k][n] = (k == n+4)
    #pragma unroll
    for (int i = 0; i < 8; ++i) {
        const int k = kg * 8 + i;
        wsB[4 * 512 + l * 8 + i] = (_Float16)((k == col + 4) ? 1.f : 0.f);
    }
    // tile 5: A2  lane holds A2[m = col][k = kg*8+i]
    #pragma unroll
    for (int i = 0; i < 8; ++i) {
        const int k = kg * 8 + i;
        const int m = col;
        float v = 0.f;
        if (m < 3) {
            if (k < 16)       v = W_mu[m * 16 + k];
            else if (k == 20) v = b_mu[m];
        } else if (m < 6) {
            if (k < 16)       v = W_lv[(m - 3) * 16 + k];
            else if (k == 20) v = b_lv[m - 3];
        }
        wsB[5 * 512 + l * 8 + i] = (_Float16)v;
    }
    if (l < 16) {
        float4* b4 = (float4*)((char*)wsv + 6144);
        b4[l] = make_float4(b_ih[l] + b_hh[l],
                            b_ih[16 + l] + b_hh[16 + l],
                            b_ih[32 + l],
                            b_hh[32 + l]);
    }
}

__global__ __launch_bounds__(TPB) void rssm_kernel(
    const float* __restrict__ prev_z,   // [B,3]
    const float* __restrict__ action,   // [B,1]
    const float* __restrict__ prev_h,   // [B,16]
    const void*  __restrict__ wsv,
    float* __restrict__ out_mu,         // [B,3]
    float* __restrict__ out_lv,         // [B,3]
    float* __restrict__ out_h,          // [B,16]
    int B)
{
    __shared__ float lds[4][LDS_WAVE_F32];
    const int tid = threadIdx.x;
    const int wid = tid >> 6, lane = tid & 63;
    const int col = lane & 15, kg = lane >> 4;
    const int wbase = (blockIdx.x * 4 + wid) * 64;
    if (wbase >= B) return;

    float* W  = lds[wid];
    float* MU = W + LDS_ROW_F32;
    float* LV = MU + LDS_MU_F32;

    // ---- wave-invariant fragments ----
    const half8* Bp = (const half8*)wsv;
    const half8 bR  = Bp[lane];
    const half8 bZ  = Bp[64 + lane];
    const half8 bNi = Bp[128 + lane];
    const half8 bNh = Bp[192 + lane];
    const half8 bHp = Bp[256 + lane];
    const half8 a2  = Bp[320 + lane];
    const float4 bias = ((const float4*)((const char*)wsv + 6144))[col];

    // ---- stage this wave's 64 rows into LDS (coalesced, wave-private) ----
    {
        const float4* hg = (const float4*)prev_h;
        #pragma unroll
        for (int i = 0; i < 4; ++i) {
            const int fi = i * 64 + lane;               // 0..255
            const int r = fi >> 2, w = fi & 3;
            const int gi = min(wbase * 4 + fi, B * 4 - 1);
            const float4 v = hg[gi];
            *(float4*)&W[r * ROW_DW + 4 + w * 4] = v;
        }
        const int zr = min(wbase + lane, B - 1);
        const float z0 = prev_z[zr * 3 + 0];
        const float z1 = prev_z[zr * 3 + 1];
        const float z2 = prev_z[zr * 3 + 2];
        const float ac = action[zr];
        *(float4*)&W[lane * ROW_DW] = make_float4(z0, z1, z2, ac);
    }
    // no barrier: each wave reads only its own LDS slice (lgkmcnt ordering)

    #pragma unroll
    for (int t = 0; t < WPT; ++t) {
        // ---- A fragment (uniform LDS reads; k>=20 lanes hold zeros) ----
        const float* ap = &W[(t * 16 + col) * ROW_DW + kg * 8];
        const float4 z4 = make_float4(0.f, 0.f, 0.f, 0.f);
        const float4 p0 = (kg < 3) ? *(const float4*)ap : z4;
        const float4 p1 = (kg < 2) ? *(const float4*)(ap + 4) : z4;
        const half8 a = pack8(p0, p1);

        f32x4 accR  = {bias.x, bias.x, bias.x, bias.x};
        f32x4 accZ  = {bias.y, bias.y, bias.y, bias.y};
        f32x4 accNi = {bias.z, bias.z, bias.z, bias.z};
        f32x4 accNh = {bias.w, bias.w, bias.w, bias.w};
        f32x4 accHp = {0.f, 0.f, 0.f, 0.f};
        accR  = __builtin_amdgcn_mfma_f32_16x16x32_f16(a, bR,  accR,  0, 0, 0);
        accZ  = __builtin_amdgcn_mfma_f32_16x16x32_f16(a, bZ,  accZ,  0, 0, 0);
        accNi = __builtin_amdgcn_mfma_f32_16x16x32_f16(a, bNi, accNi, 0, 0, 0);
        accNh = __builtin_amdgcn_mfma_f32_16x16x32_f16(a, bNh, accNh, 0, 0, 0);
        accHp = __builtin_amdgcn_mfma_f32_16x16x32_f16(a, bHp, accHp, 0, 0, 0);

        // ---- gates; write hn back into the LDS h-slot ----
        #pragma unroll
        for (int q = 0; q < 4; ++q) {
            const float r  = fast_sigmoid(accR[q]);
            const float z  = fast_sigmoid(accZ[q]);
            const float n  = fast_tanh(fmaf(r, accNh[q], accNi[q]));
            const float hv = fmaf(z, accHp[q] - n, n);   // (1-z)*n + z*h
            W[(t * 16 + kg * 4 + q) * ROW_DW + 4 + col] = hv;
        }

        // ---- head MFMA: B2[k][n=col] = hn[col][k] ----
        half8 b2;
        if (kg < 2) {
            const float* hr = &W[(t * 16 + col) * ROW_DW + 4 + kg * 8];
            b2 = pack8(*(const float4*)hr, *(const float4*)(hr + 4));
        } else {
            #pragma unroll
            for (int i = 0; i < 8; ++i) b2[i] = (_Float16)0.f;
            if (kg == 2) b2[4] = (_Float16)1.0f;         // k=20 bias slot
        }
        f32x4 acc2 = {0.f, 0.f, 0.f, 0.f};
        acc2 = __builtin_amdgcn_mfma_f32_16x16x32_f16(a2, b2, acc2, 0, 0, 0);

        // mu/lv into LDS (clamped), packed [row][3] per stream
        const int mr = (t * 16 + col) * 3;
        if (kg == 0) {
            MU[mr + 0] = acc2[0];
            MU[mr + 1] = acc2[1];
            MU[mr + 2] = acc2[2];
            LV[mr + 0] = fminf(fmaxf(acc2[3], -5.0f), 5.0f);
        } else if (kg == 1) {
            LV[mr + 1] = fminf(fmaxf(acc2[0], -5.0f), 5.0f);
            LV[mr + 2] = fminf(fmaxf(acc2[1], -5.0f), 5.0f);
        }

        // ---- cooperative out_h store for this tile (1 KB contiguous) ----
        {
            const int r = lane >> 2, w = lane & 3;
            const float4 hv4 = *(const float4*)&W[(t * 16 + r) * ROW_DW + 4 + w * 4];
            const int orow = wbase + t * 16 + r;
            if (orow < B)
                *(float4*)&out_h[(size_t)orow * 16 + w * 4] = hv4;
        }
    }

    // ---- cooperative mu / lv stores (768 B contiguous each) ----
    if (lane < 48) {
        const int gi = wbase * 3 + lane * 4;
        if (gi + 3 < B * 3) {
            *(float4*)&out_mu[gi] = *(const float4*)&MU[lane * 4];
            *(float4*)&out_lv[gi] = *(const float4*)&LV[lane * 4];
        }
    }
}

extern "C" void kernel_launch(void* const* d_in, const int* in_sizes, int n_in,
                              void* d_out, int out_size, void* d_ws, size_t ws_size,
                              hipStream_t stream) {
    const float* prev_z = (const float*)d_in[0];
    const float* action = (const float*)d_in[1];
    const float* prev_h = (const float*)d_in[2];
    const float* W_ih   = (const float*)d_in[3];
    const float* W_hh   = (const float*)d_in[4];
    const float* b_ih   = (const float*)d_in[5];
    const float* b_hh   = (const float*)d_in[6];
    const float* W_mu   = (const float*)d_in[7];
    const float* b_mu   = (const float*)d_in[8];
    const float* W_lv   = (const float*)d_in[9];
    const float* b_lv   = (const float*)d_in[10];

    const int B = in_sizes[0] / 3;
    float* out    = (float*)d_out;
    float* out_mu = out;
    float* out_lv = out + (size_t)3 * B;
    float* out_h  = out + (size_t)6 * B;

    prep_kernel<<<1, 64, 0, stream>>>(W_ih, W_hh, b_ih, b_hh,
                                      W_mu, b_mu, W_lv, b_lv, d_ws);

    const int rows_per_block = 256;
    const int blocks = (B + rows_per_block - 1) / rows_per_block;
    rssm_kernel<<<blocks, TPB, 0, stream>>>(prev_z, action, prev_h, d_ws,
                                            out_mu, out_lv, out_h, B);
}